// Round 2
// baseline (27718.616 us; speedup 1.0000x reference)
//
#include <hip/hip_runtime.h>
#include <hip/hip_bf16.h>

typedef __attribute__((ext_vector_type(8))) short short8;
typedef __attribute__((ext_vector_type(4))) float f32x4;

#define SEQ   256   // source length S
#define BB    16    // batch
#define EE    256   // embed dim
#define HH    256   // hidden
#define GG    1024  // 4*H
#define TT    128   // target_size
#define KPAD  264   // row stride in bf16 elems (528 B, 16B-aligned)

__device__ __forceinline__ float sigm(float x) { return 1.0f / (1.0f + __expf(-x)); }
__device__ __forceinline__ float tanh_f(float x) {
    float e = __expf(2.0f * x);
    return 1.0f - 2.0f / (e + 1.0f);
}
__device__ __forceinline__ void split2(float v, __hip_bfloat16* hi, __hip_bfloat16* lo) {
    __hip_bfloat16 h = __float2bfloat16(v);
    *hi = h;
    *lo = __float2bfloat16(v - __bfloat162float(h));
}
__device__ __forceinline__ f32x4 MFMA(short8 a, short8 b, f32x4 c) {
    return __builtin_amdgcn_mfma_f32_16x16x32_bf16(a, b, c, 0, 0, 0);
}

// ---------------- utility kernels ----------------
__global__ void k_cvt2(const float* __restrict__ s, __hip_bfloat16* __restrict__ hi,
                       __hip_bfloat16* __restrict__ lo, int n) {
    int i = blockIdx.x * 256 + threadIdx.x;
    if (i < n) split2(s[i], hi + i, lo + i);
}

__global__ void k_zero(float* __restrict__ p) {
    p[blockIdx.x * 256 + threadIdx.x] = 0.0f;
}

__global__ void k_embed(const int* __restrict__ src, const float* __restrict__ tab,
                        __hip_bfloat16* __restrict__ xhi, __hip_bfloat16* __restrict__ xlo) {
    int r = blockIdx.x;          // r = t*B + b
    int j = threadIdx.x;
    long idx = src[r];
    split2(tab[idx * EE + j], &xhi[(long)r * EE + j], &xlo[(long)r * EE + j]);
}

// ------------- input-side GEMM: gates = X @ W^T + bih + bhh (split-bf16 f32-accurate) -------------
__global__ void __launch_bounds__(256) k_gemm_in(
        const __hip_bfloat16* __restrict__ Xhi, const __hip_bfloat16* __restrict__ Xlo,
        const __hip_bfloat16* __restrict__ Whi, const __hip_bfloat16* __restrict__ Wlo,
        const float* __restrict__ bih, const float* __restrict__ bhh,
        float* __restrict__ gates) {
    int lane = threadIdx.x & 63, w = threadIdx.x >> 6;
    int m0 = (blockIdx.x >> 4) * 16;
    int n0 = ((blockIdx.x & 15) * 4 + w) * 16;
    int cc = lane & 15, g = lane >> 4;
    int koff = g * 8;
    const short* xh = (const short*)Xhi + (long)(m0 + cc) * EE + koff;
    const short* xl = (const short*)Xlo + (long)(m0 + cc) * EE + koff;
    const short* wh = (const short*)Whi + (long)(n0 + cc) * EE + koff;
    const short* wl = (const short*)Wlo + (long)(n0 + cc) * EE + koff;
    f32x4 acc = {0.f, 0.f, 0.f, 0.f};
#pragma unroll
    for (int k = 0; k < EE; k += 32) {
        short8 ah = *(const short8*)(xh + k), al = *(const short8*)(xl + k);
        short8 bh = *(const short8*)(wh + k), bl = *(const short8*)(wl + k);
        acc = MFMA(ah, bh, acc);
        acc = MFMA(ah, bl, acc);
        acc = MFMA(al, bh, acc);
    }
    int ncol = n0 + cc;
    float bias = bih[ncol] + bhh[ncol];
    int mrow = m0 + g * 4;
#pragma unroll
    for (int r = 0; r < 4; ++r)
        gates[(long)(mrow + r) * GG + ncol] = acc[r] + bias;
}

// ---------------- encoder layer scan (1 WG, 1024 thr; gates stay in f32 regs) ----------------
// Wave w owns output cols jj = w*16 + (lane&15) of ALL four gates, so each thread's
// acc[q][r] is gate q at (b = 4*(lane>>4)+r, jj): the LSTM pointwise runs in-register.
__global__ void __launch_bounds__(1024) k_enc_scan(
        const float* __restrict__ gates_in,                 // [S*B, G] f32 (bias folded)
        const __hip_bfloat16* __restrict__ Whh_hi, const __hip_bfloat16* __restrict__ Whh_lo,
        const float* __restrict__ h0, const float* __restrict__ c0,
        __hip_bfloat16* __restrict__ xout_hi, __hip_bfloat16* __restrict__ xout_lo,
        float* __restrict__ hfin) {
    __shared__ alignas(16) __hip_bfloat16 hhi[BB][KPAD];
    __shared__ alignas(16) __hip_bfloat16 hlo[BB][KPAD];

    int tid = threadIdx.x, lane = tid & 63, w = tid >> 6;
    int g = lane >> 4, cc = lane & 15;
    int jj = w * 16 + cc;        // owned column (both C/D col and A-k base col)
    int koff = g * 8;

    float c_reg[4], h_reg[4];
#pragma unroll
    for (int r = 0; r < 4; ++r) {
        int b = 4 * g + r;
        float hv = h0[b * HH + jj];
        c_reg[r] = c0[b * HH + jj];
        h_reg[r] = hv;
        __hip_bfloat16 sh, sl;
        split2(hv, &sh, &sl);
        hhi[b][jj] = sh; hlo[b][jj] = sl;
    }
    __syncthreads();

    for (int t = 0; t < SEQ; ++t) {
        f32x4 acc[4];
#pragma unroll
        for (int q = 0; q < 4; ++q)
#pragma unroll
            for (int r = 0; r < 4; ++r)
                acc[q][r] = gates_in[(long)(t * BB + 4 * g + r) * GG + q * 256 + jj];

        const short* AH = (const short*)&hhi[cc][0];
        const short* AL = (const short*)&hlo[cc][0];
        for (int k = 0; k < EE; k += 32) {
            short8 ah = *(const short8*)(AH + k + koff);
            short8 al = *(const short8*)(AL + k + koff);
#pragma unroll
            for (int q = 0; q < 4; ++q) {
                long wr = (long)(q * 256 + jj) * EE + k + koff;
                short8 bh = *(const short8*)((const short*)Whh_hi + wr);
                short8 bl = *(const short8*)((const short*)Whh_lo + wr);
                acc[q] = MFMA(ah, bh, acc[q]);
                acc[q] = MFMA(ah, bl, acc[q]);
                acc[q] = MFMA(al, bh, acc[q]);
            }
        }
        __syncthreads();   // all LDS reads of h done before overwrite
#pragma unroll
        for (int r = 0; r < 4; ++r) {
            int b = 4 * g + r;
            float c = sigm(acc[1][r]) * c_reg[r] + sigm(acc[0][r]) * tanh_f(acc[2][r]);
            c_reg[r] = c;
            float h = sigm(acc[3][r]) * tanh_f(c);
            h_reg[r] = h;
            __hip_bfloat16 sh, sl;
            split2(h, &sh, &sl);
            hhi[b][jj] = sh; hlo[b][jj] = sl;
            if (xout_hi) {
                long o = (long)(t * BB + b) * EE + jj;
                xout_hi[o] = sh; xout_lo[o] = sl;
            }
        }
        __syncthreads();
    }

#pragma unroll
    for (int r = 0; r < 4; ++r) {
        int b = 4 * g + r;
        hfin[b * HH + jj] = h_reg[r];
    }
}

// ---------------- decoder scan (1 WG, 1024 thr) ----------------
__global__ void __launch_bounds__(1024) k_dec_scan(
        const float* __restrict__ te,            // target_embeddings[0,0,:]
        const float* __restrict__ hfin,          // [2,16,256] f32
        const __hip_bfloat16* __restrict__ Wih_hi, const __hip_bfloat16* __restrict__ Wih_lo,
        const __hip_bfloat16* __restrict__ Whh_hi, const __hip_bfloat16* __restrict__ Whh_lo,
        const float* __restrict__ bih, const float* __restrict__ bhh,
        float* __restrict__ preds) {
    __shared__ alignas(16) __hip_bfloat16 xhi[BB][KPAD], xlo[BB][KPAD];
    __shared__ alignas(16) __hip_bfloat16 hhi[2][BB][KPAD], hlo[2][BB][KPAD];

    const int WN = GG * EE;
    int tid = threadIdx.x, lane = tid & 63, w = tid >> 6;
    int g = lane >> 4, cc = lane & 15;
    int jj = w * 16 + cc;
    int koff = g * 8;

    float c_reg[2][4];
    float bsum[2][4];
#pragma unroll
    for (int r = 0; r < 4; ++r) {
        int b = 4 * g + r;
        __hip_bfloat16 sh, sl;
        split2(te[jj], &sh, &sl);
        xhi[b][jj] = sh; xlo[b][jj] = sl;
#pragma unroll
        for (int l = 0; l < 2; ++l) {
            float hv = hfin[l * (BB * HH) + b * HH + jj];
            c_reg[l][r] = hv;                     // source bug: c := h
            split2(hv, &sh, &sl);
            hhi[l][b][jj] = sh; hlo[l][b][jj] = sl;
        }
    }
#pragma unroll
    for (int l = 0; l < 2; ++l)
#pragma unroll
        for (int q = 0; q < 4; ++q)
            bsum[l][q] = bih[l * GG + q * 256 + jj] + bhh[l * GG + q * 256 + jj];
    __syncthreads();

    for (int t = 0; t < TT - 1; ++t) {
#pragma unroll
        for (int l = 0; l < 2; ++l) {
            f32x4 acc[4];
#pragma unroll
            for (int q = 0; q < 4; ++q) {
                float bv = bsum[l][q];
                f32x4 tv = {bv, bv, bv, bv};
                acc[q] = tv;
            }
            const short* AXH = (const short*)(l == 0 ? &xhi[cc][0] : &hhi[0][cc][0]);
            const short* AXL = (const short*)(l == 0 ? &xlo[cc][0] : &hlo[0][cc][0]);
            const short* AHH = (const short*)&hhi[l][cc][0];
            const short* AHL = (const short*)&hlo[l][cc][0];
            const short* WIH = (const short*)Wih_hi + (long)l * WN;
            const short* WIL = (const short*)Wih_lo + (long)l * WN;
            const short* WHH = (const short*)Whh_hi + (long)l * WN;
            const short* WHL = (const short*)Whh_lo + (long)l * WN;
            for (int k = 0; k < EE; k += 32) {
                short8 axh = *(const short8*)(AXH + k + koff);
                short8 axl = *(const short8*)(AXL + k + koff);
                short8 ahh = *(const short8*)(AHH + k + koff);
                short8 ahl = *(const short8*)(AHL + k + koff);
#pragma unroll
                for (int q = 0; q < 4; ++q) {
                    long wr = (long)(q * 256 + jj) * EE + k + koff;
                    short8 b1 = *(const short8*)(WIH + wr);
                    short8 b2 = *(const short8*)(WIL + wr);
                    short8 b3 = *(const short8*)(WHH + wr);
                    short8 b4 = *(const short8*)(WHL + wr);
                    acc[q] = MFMA(axh, b1, acc[q]);
                    acc[q] = MFMA(axh, b2, acc[q]);
                    acc[q] = MFMA(axl, b1, acc[q]);
                    acc[q] = MFMA(ahh, b3, acc[q]);
                    acc[q] = MFMA(ahh, b4, acc[q]);
                    acc[q] = MFMA(ahl, b3, acc[q]);
                }
            }
            __syncthreads();   // all LDS reads done before overwrite
#pragma unroll
            for (int r = 0; r < 4; ++r) {
                int b = 4 * g + r;
                float c = sigm(acc[1][r]) * c_reg[l][r] + sigm(acc[0][r]) * tanh_f(acc[2][r]);
                c_reg[l][r] = c;
                float h = sigm(acc[3][r]) * tanh_f(c);
                __hip_bfloat16 sh, sl;
                split2(h, &sh, &sl);
                hhi[l][b][jj] = sh; hlo[l][b][jj] = sl;
                if (l == 1) {
                    xhi[b][jj] = sh; xlo[b][jj] = sl;
                    preds[((long)(t + 1) * BB + b) * HH + jj] = h;
                }
            }
            __syncthreads();
        }
    }
}

// ---------------- host launch ----------------
extern "C" void kernel_launch(void* const* d_in, const int* in_sizes, int n_in,
                              void* d_out, int out_size, void* d_ws, size_t ws_size,
                              hipStream_t stream) {
    const int*   src   = (const int*)  d_in[0];
    const float* te    = (const float*)d_in[2];
    const float* h0    = (const float*)d_in[3];
    const float* c0    = (const float*)d_in[4];
    const float* table = (const float*)d_in[5];
    const float* eWih  = (const float*)d_in[6];
    const float* eWhh  = (const float*)d_in[7];
    const float* ebih  = (const float*)d_in[8];
    const float* ebhh  = (const float*)d_in[9];
    const float* dWih  = (const float*)d_in[10];
    const float* dWhh  = (const float*)d_in[11];
    const float* dbih  = (const float*)d_in[12];
    const float* dbhh  = (const float*)d_in[13];
    float* preds = (float*)d_out;

    const int WN = GG * EE;                  // 262144 elems per layer-matrix
    const size_t MB = 1u << 20;
    char* ws = (char*)d_ws;
    __hip_bfloat16* eWih_hi = (__hip_bfloat16*)(ws + 0 * MB);
    __hip_bfloat16* eWih_lo = (__hip_bfloat16*)(ws + 1 * MB);
    __hip_bfloat16* eWhh_hi = (__hip_bfloat16*)(ws + 2 * MB);
    __hip_bfloat16* eWhh_lo = (__hip_bfloat16*)(ws + 3 * MB);
    __hip_bfloat16* dWih_hi = (__hip_bfloat16*)(ws + 4 * MB);
    __hip_bfloat16* dWih_lo = (__hip_bfloat16*)(ws + 5 * MB);
    __hip_bfloat16* dWhh_hi = (__hip_bfloat16*)(ws + 6 * MB);
    __hip_bfloat16* dWhh_lo = (__hip_bfloat16*)(ws + 7 * MB);
    __hip_bfloat16* Xa_hi   = (__hip_bfloat16*)(ws + 8 * MB);   // [4096,256] = 2 MB
    __hip_bfloat16* Xa_lo   = (__hip_bfloat16*)(ws + 10 * MB);
    __hip_bfloat16* Xb_hi   = (__hip_bfloat16*)(ws + 12 * MB);
    __hip_bfloat16* Xb_lo   = (__hip_bfloat16*)(ws + 14 * MB);
    float*          gates   = (float*)        (ws + 16 * MB);   // [4096,1024] f32 = 16 MB
    float*          hfin    = (float*)        (ws + 32 * MB);   // [2,16,256] f32

    // weight hi/lo split (2 layers contiguous per tensor)
    k_cvt2<<<2048, 256, 0, stream>>>(eWih, eWih_hi, eWih_lo, 2 * WN);
    k_cvt2<<<2048, 256, 0, stream>>>(eWhh, eWhh_hi, eWhh_lo, 2 * WN);
    k_cvt2<<<2048, 256, 0, stream>>>(dWih, dWih_hi, dWih_lo, 2 * WN);
    k_cvt2<<<2048, 256, 0, stream>>>(dWhh, dWhh_hi, dWhh_lo, 2 * WN);

    // encoder
    k_embed<<<4096, 256, 0, stream>>>(src, table, Xa_hi, Xa_lo);
    k_gemm_in<<<4096, 256, 0, stream>>>(Xa_hi, Xa_lo, eWih_hi, eWih_lo, ebih, ebhh, gates);
    k_enc_scan<<<1, 1024, 0, stream>>>(gates, eWhh_hi, eWhh_lo, h0, c0, Xb_hi, Xb_lo, hfin);
    k_gemm_in<<<4096, 256, 0, stream>>>(Xb_hi, Xb_lo, eWih_hi + WN, eWih_lo + WN,
                                        ebih + GG, ebhh + GG, gates);
    k_enc_scan<<<1, 1024, 0, stream>>>(gates, eWhh_hi + WN, eWhh_lo + WN,
                                       h0 + BB * HH, c0 + BB * HH, nullptr, nullptr,
                                       hfin + BB * HH);

    // decoder
    k_dec_scan<<<1, 1024, 0, stream>>>(te, hfin, dWih_hi, dWih_lo, dWhh_hi, dWhh_lo,
                                       dbih, dbhh, preds);
    // predictions[0] = 0
    k_zero<<<16, 256, 0, stream>>>(preds);
}

// Round 3
// 3273.133 us; speedup vs baseline: 8.4685x; 8.4685x over previous
//
#include <hip/hip_runtime.h>
#include <hip/hip_bf16.h>

typedef __attribute__((ext_vector_type(8))) short short8;
typedef __attribute__((ext_vector_type(4))) float f32x4;

#define SEQ   256   // source length S
#define BB    16    // batch
#define EE    256   // embed dim
#define HH    256   // hidden
#define GG    1024  // 4*H
#define TT    128   // target_size
#define NWG   32    // persistent workgroups
#define KP    264   // LDS row stride in shorts (breaks 512B-stride bank conflicts)

__device__ __forceinline__ float sigm(float x) { return 1.0f / (1.0f + __expf(-x)); }
__device__ __forceinline__ float tanh_f(float x) {
    float e = __expf(2.0f * x);
    return 1.0f - 2.0f / (e + 1.0f);
}
__device__ __forceinline__ void split2s(float v, short* hi, short* lo) {
    __hip_bfloat16 h = __float2bfloat16(v);
    __hip_bfloat16 l = __float2bfloat16(v - __bfloat162float(h));
    *hi = *(short*)&h; *lo = *(short*)&l;
}
__device__ __forceinline__ f32x4 MFMA(short8 a, short8 b, f32x4 c) {
    return __builtin_amdgcn_mfma_f32_16x16x32_bf16(a, b, c, 0, 0, 0);
}

// ---- grid barrier: flag-array, 32 independent release-stores, 64-lane poll ----
__device__ __forceinline__ void gbar(int* flags, int target) {
    __syncthreads();
    if (threadIdx.x < 64) {
        if (threadIdx.x == 0) {
            __threadfence();   // L2 writeback: make this block's stores device-visible
            __hip_atomic_store(&flags[blockIdx.x], target, __ATOMIC_RELEASE,
                               __HIP_MEMORY_SCOPE_AGENT);
        }
        int i = threadIdx.x & 31;
        while (__hip_atomic_load(&flags[i], __ATOMIC_ACQUIRE,
                                 __HIP_MEMORY_SCOPE_AGENT) < target)
            __builtin_amdgcn_s_sleep(1);
        __threadfence();       // invalidate local caches before post-barrier reads
    }
    __syncthreads();
}

// ---------------- utility kernels ----------------
__global__ void k_binit(int* p) { if (threadIdx.x < 64) p[threadIdx.x] = 0; }

__global__ void k_cvt2(const float* __restrict__ s, __hip_bfloat16* __restrict__ hi,
                       __hip_bfloat16* __restrict__ lo, int n) {
    int i = blockIdx.x * 256 + threadIdx.x;
    if (i < n) {
        short a, b; split2s(s[i], &a, &b);
        hi[i] = *(__hip_bfloat16*)&a; lo[i] = *(__hip_bfloat16*)&b;
    }
}

__global__ void k_zero(float* __restrict__ p) {
    p[blockIdx.x * 256 + threadIdx.x] = 0.0f;
}

__global__ void k_embed(const int* __restrict__ src, const float* __restrict__ tab,
                        __hip_bfloat16* __restrict__ xhi, __hip_bfloat16* __restrict__ xlo) {
    int r = blockIdx.x;          // r = t*B + b
    int j = threadIdx.x;
    long idx = src[r];
    short a, b; split2s(tab[idx * EE + j], &a, &b);
    xhi[(long)r * EE + j] = *(__hip_bfloat16*)&a;
    xlo[(long)r * EE + j] = *(__hip_bfloat16*)&b;
}

// ------------- input-side GEMM: gates0 = X @ Wih0^T + bih0 + bhh0 (f32-accurate) -------------
__global__ void __launch_bounds__(256) k_gemm_in(
        const __hip_bfloat16* __restrict__ Xhi, const __hip_bfloat16* __restrict__ Xlo,
        const __hip_bfloat16* __restrict__ Whi, const __hip_bfloat16* __restrict__ Wlo,
        const float* __restrict__ bih, const float* __restrict__ bhh,
        float* __restrict__ gates) {
    int lane = threadIdx.x & 63, w = threadIdx.x >> 6;
    int m0 = (blockIdx.x >> 4) * 16;
    int n0 = ((blockIdx.x & 15) * 4 + w) * 16;
    int cc = lane & 15, g = lane >> 4;
    int koff = g * 8;
    const short* xh = (const short*)Xhi + (long)(m0 + cc) * EE + koff;
    const short* xl = (const short*)Xlo + (long)(m0 + cc) * EE + koff;
    const short* wh = (const short*)Whi + (long)(n0 + cc) * EE + koff;
    const short* wl = (const short*)Wlo + (long)(n0 + cc) * EE + koff;
    f32x4 acc = {0.f, 0.f, 0.f, 0.f};
#pragma unroll
    for (int k = 0; k < EE; k += 32) {
        short8 ah = *(const short8*)(xh + k), al = *(const short8*)(xl + k);
        short8 bh = *(const short8*)(wh + k), bl = *(const short8*)(wl + k);
        acc = MFMA(ah, bh, acc);
        acc = MFMA(ah, bl, acc);
        acc = MFMA(al, bh, acc);
    }
    int ncol = n0 + cc;
    float bias = bih[ncol] + bhh[ncol];
    int mrow = m0 + g * 4;
#pragma unroll
    for (int r = 0; r < 4; ++r)
        gates[(long)(mrow + r) * GG + ncol] = acc[r] + bias;
}

// ---- gather one 32-row weight slice (rows q*256+j0+jl -> lr=q*8+jl) into LDS ----
__device__ __forceinline__ void load_wslice(const short* __restrict__ Wg, int j0,
                                            short* __restrict__ Wl) {
    int tid = threadIdx.x;
    int lr = tid >> 3;                 // 0..31
    int q = lr >> 3, jl = lr & 7;
    const short* src = Wg + (long)(q * 256 + j0 + jl) * 256;
    short* dst = Wl + lr * KP;
#pragma unroll
    for (int s = 0; s < 4; ++s) {
        int c = (tid & 7) * 8 + s * 64;
        *(short8*)(dst + c) = *(const short8*)(src + c);
    }
}

// ---------------- encoder: both layers, wavefront (L1 one step behind L0) ----------------
// 32 blocks x 256 thr. Block owns hidden j0..j0+7 (both layers). Weights LDS-resident.
__global__ void __launch_bounds__(256) k_enc_coop(
        const float* __restrict__ gates0,                  // [S*B][G] L0 x-gates + bias
        const short* __restrict__ Whh0h, const short* __restrict__ Whh0l,
        const short* __restrict__ Wih1h, const short* __restrict__ Wih1l,
        const short* __restrict__ Whh1h, const short* __restrict__ Whh1l,
        const float* __restrict__ bih1, const float* __restrict__ bhh1,
        const float* __restrict__ h0p, const float* __restrict__ c0p,  // [2][16][256]
        short* __restrict__ h0bh, short* __restrict__ h0bl,  // [2][4096] double buf
        short* __restrict__ h1bh, short* __restrict__ h1bl,
        float* __restrict__ hfin, int* __restrict__ flags) {
    __shared__ short Wl[6][32 * KP];
    __shared__ float gacc[4][16][17];

    int tid = threadIdx.x;
    int j0 = blockIdx.x * 8;
    load_wslice(Whh0h, j0, Wl[0]); load_wslice(Whh0l, j0, Wl[1]);
    load_wslice(Wih1h, j0, Wl[2]); load_wslice(Wih1l, j0, Wl[3]);
    load_wslice(Whh1h, j0, Wl[4]); load_wslice(Whh1l, j0, Wl[5]);

    int bb = (tid & 127) >> 3, jl = tid & 7, j = j0 + jl, lay = tid >> 7;
    float creg = c0p[lay * 4096 + bb * 256 + j];
    float bs[4] = {0.f, 0.f, 0.f, 0.f};
    if (lay) {
#pragma unroll
        for (int q = 0; q < 4; ++q) bs[q] = bih1[q * 256 + j] + bhh1[q * 256 + j];
    }
    {   // init: L0 state -> buf1 (read at i=0), L1 state -> buf0 (read at i=1)
        float hv = h0p[lay * 4096 + bb * 256 + j];
        short sh, sl; split2s(hv, &sh, &sl);
        short* dh = lay ? h1bh : (h0bh + 4096);
        short* dl = lay ? h1bl : (h0bl + 4096);
        dh[bb * 256 + j] = sh; dl[bb * 256 + j] = sl;
    }
    int gen = 0;
    gbar(flags, ++gen);

    int lane = tid & 63, w = tid >> 6, cc = lane & 15, g4 = lane >> 4, koff = g4 * 8;

    for (int i = 0; i <= SEQ; ++i) {
        int rb = (i + 1) & 1, wb = i & 1;
        f32x4 acc = {0.f, 0.f, 0.f, 0.f};
        if (w < 2) {                       // L0 tile w, full K, A = h0 state
            if (i < SEQ) {
                int aoff = rb * 4096 + cc * 256 + koff;
                int woff = (w * 16 + cc) * KP + koff;
                const short *ah = h0bh + aoff, *al = h0bl + aoff;
#pragma unroll
                for (int k = 0; k < 256; k += 32) {
                    short8 vh = *(const short8*)(ah + k), vl = *(const short8*)(al + k);
                    short8 wh = *(const short8*)(Wl[0] + woff + k);
                    short8 wl2 = *(const short8*)(Wl[1] + woff + k);
                    acc = MFMA(vh, wh, acc); acc = MFMA(vh, wl2, acc); acc = MFMA(vl, wh, acc);
                }
            }
        } else if (i >= 1) {               // L1 tile w-2, x = h0(prev) , h = h1 state
            int tw = w - 2;
            int aoff = rb * 4096 + cc * 256 + koff;
            int woff = (tw * 16 + cc) * KP + koff;
            const short *xh = h0bh + aoff, *xl = h0bl + aoff;
            const short *hh = h1bh + aoff, *hl = h1bl + aoff;
#pragma unroll
            for (int k = 0; k < 256; k += 32) {
                short8 vxh = *(const short8*)(xh + k), vxl = *(const short8*)(xl + k);
                acc = MFMA(vxh, *(const short8*)(Wl[2] + woff + k), acc);
                acc = MFMA(vxh, *(const short8*)(Wl[3] + woff + k), acc);
                acc = MFMA(vxl, *(const short8*)(Wl[2] + woff + k), acc);
                short8 vhh = *(const short8*)(hh + k), vhl = *(const short8*)(hl + k);
                acc = MFMA(vhh, *(const short8*)(Wl[4] + woff + k), acc);
                acc = MFMA(vhh, *(const short8*)(Wl[5] + woff + k), acc);
                acc = MFMA(vhl, *(const short8*)(Wl[4] + woff + k), acc);
            }
        }
#pragma unroll
        for (int r = 0; r < 4; ++r) gacc[w][g4 * 4 + r][cc] = acc[r];
        __syncthreads();

        bool act = lay ? (i >= 1) : (i < SEQ);
        if (act) {
            int t = lay ? (i - 1) : i;
            float gv[4];
#pragma unroll
            for (int q = 0; q < 4; ++q) {
                int lr = q * 8 + jl;
                float v = gacc[lay * 2 + (lr >> 4)][bb][lr & 15] + bs[q];
                if (!lay) v += gates0[(long)(t * BB + bb) * GG + q * 256 + j];
                gv[q] = v;
            }
            float c = sigm(gv[1]) * creg + sigm(gv[0]) * tanh_f(gv[2]);
            creg = c;
            float h = sigm(gv[3]) * tanh_f(c);
            short sh, sl; split2s(h, &sh, &sl);
            short* dh = (lay ? h1bh : h0bh) + wb * 4096;
            short* dl = (lay ? h1bl : h0bl) + wb * 4096;
            dh[bb * 256 + j] = sh; dl[bb * 256 + j] = sl;
            if (t == SEQ - 1) hfin[lay * 4096 + bb * 256 + j] = h;
        }
        gbar(flags, ++gen);
    }
}

// ---------------- decoder: 2 phases/step (L0 then L1), weights LDS-resident ----------------
__global__ void __launch_bounds__(256) k_dec_coop(
        const short* __restrict__ Wihh, const short* __restrict__ Wihl,   // [2][1024][256]
        const short* __restrict__ Whhh, const short* __restrict__ Whhl,
        const float* __restrict__ dbih, const float* __restrict__ dbhh,   // [2][1024]
        const float* __restrict__ tef, const float* __restrict__ hfin,
        short* __restrict__ h0bh, short* __restrict__ h0bl,   // [2][4096]
        short* __restrict__ h1bh, short* __restrict__ h1bl,
        short* __restrict__ teh, short* __restrict__ tel,     // [4096] init bufs
        short* __restrict__ h0ih, short* __restrict__ h0il,
        short* __restrict__ h1ih, short* __restrict__ h1il,
        float* __restrict__ preds, int* __restrict__ flags) {
    __shared__ short Wl[8][32 * KP];
    __shared__ float gacc[4][16][17];
    const int WN = GG * EE;

    int tid = threadIdx.x;
    int j0 = blockIdx.x * 8;
    load_wslice(Wihh, j0, Wl[0]);      load_wslice(Wihl, j0, Wl[1]);
    load_wslice(Whhh, j0, Wl[2]);      load_wslice(Whhl, j0, Wl[3]);
    load_wslice(Wihh + WN, j0, Wl[4]); load_wslice(Wihl + WN, j0, Wl[5]);
    load_wslice(Whhh + WN, j0, Wl[6]); load_wslice(Whhl + WN, j0, Wl[7]);

    int bb = (tid & 127) >> 3, jl = tid & 7, j = j0 + jl;
    float c0r = 0.f, c1r = 0.f;
    float bs0[4] = {0,0,0,0}, bs1[4] = {0,0,0,0};
    if (tid < 128) {
        float h0v = hfin[bb * 256 + j], h1v = hfin[4096 + bb * 256 + j];
        c0r = h0v; c1r = h1v;                      // source bug: c := h
        short sh, sl;
        split2s(tef[j], &sh, &sl); teh[bb*256+j] = sh; tel[bb*256+j] = sl;
        split2s(h0v, &sh, &sl);    h0ih[bb*256+j] = sh; h0il[bb*256+j] = sl;
        split2s(h1v, &sh, &sl);    h1ih[bb*256+j] = sh; h1il[bb*256+j] = sl;
#pragma unroll
        for (int q = 0; q < 4; ++q) {
            bs0[q] = dbih[q*256+j] + dbhh[q*256+j];
            bs1[q] = dbih[GG + q*256+j] + dbhh[GG + q*256+j];
        }
    }
    int gen = 0;
    gbar(flags, ++gen);

    int lane = tid & 63, w = tid >> 6, cc = lane & 15, g4 = lane >> 4, koff = g4 * 8;
    int tw = w & 1, kb = (w >> 1) * 128;       // tile / K-half per wave
    int aoff0 = cc * 256 + kb + koff;
    int woff = (tw * 16 + cc) * KP + kb + koff;

    for (int t = 0; t < TT - 1; ++t) {
        int pb = (t - 1) & 1;
        // ---- phase A: layer 0 ----
        {
            const short* xh = (t ? h1bh + pb * 4096 : teh) + aoff0;
            const short* xl = (t ? h1bl + pb * 4096 : tel) + aoff0;
            const short* hh = (t ? h0bh + pb * 4096 : h0ih) + aoff0;
            const short* hl = (t ? h0bl + pb * 4096 : h0il) + aoff0;
            f32x4 acc = {0.f, 0.f, 0.f, 0.f};
#pragma unroll
            for (int k = 0; k < 128; k += 32) {
                short8 a = *(const short8*)(xh + k), b = *(const short8*)(xl + k);
                acc = MFMA(a, *(const short8*)(Wl[0] + woff + k), acc);
                acc = MFMA(a, *(const short8*)(Wl[1] + woff + k), acc);
                acc = MFMA(b, *(const short8*)(Wl[0] + woff + k), acc);
                short8 c = *(const short8*)(hh + k), d = *(const short8*)(hl + k);
                acc = MFMA(c, *(const short8*)(Wl[2] + woff + k), acc);
                acc = MFMA(c, *(const short8*)(Wl[3] + woff + k), acc);
                acc = MFMA(d, *(const short8*)(Wl[2] + woff + k), acc);
            }
#pragma unroll
            for (int r = 0; r < 4; ++r) gacc[w][g4 * 4 + r][cc] = acc[r];
        }
        __syncthreads();
        if (tid < 128) {
            float gv[4];
#pragma unroll
            for (int q = 0; q < 4; ++q) {
                int lr = q * 8 + jl;
                gv[q] = gacc[lr >> 4][bb][lr & 15] + gacc[2 + (lr >> 4)][bb][lr & 15] + bs0[q];
            }
            float c = sigm(gv[1]) * c0r + sigm(gv[0]) * tanh_f(gv[2]);
            c0r = c;
            float h = sigm(gv[3]) * tanh_f(c);
            short sh, sl; split2s(h, &sh, &sl);
            h0bh[(t & 1) * 4096 + bb * 256 + j] = sh;
            h0bl[(t & 1) * 4096 + bb * 256 + j] = sl;
        }
        gbar(flags, ++gen);
        // ---- phase B: layer 1 ----
        {
            const short* xh = h0bh + (t & 1) * 4096 + aoff0;
            const short* xl = h0bl + (t & 1) * 4096 + aoff0;
            const short* hh = (t ? h1bh + pb * 4096 : h1ih) + aoff0;
            const short* hl = (t ? h1bl + pb * 4096 : h1il) + aoff0;
            f32x4 acc = {0.f, 0.f, 0.f, 0.f};
#pragma unroll
            for (int k = 0; k < 128; k += 32) {
                short8 a = *(const short8*)(xh + k), b = *(const short8*)(xl + k);
                acc = MFMA(a, *(const short8*)(Wl[4] + woff + k), acc);
                acc = MFMA(a, *(const short8*)(Wl[5] + woff + k), acc);
                acc = MFMA(b, *(const short8*)(Wl[4] + woff + k), acc);
                short8 c = *(const short8*)(hh + k), d = *(const short8*)(hl + k);
                acc = MFMA(c, *(const short8*)(Wl[6] + woff + k), acc);
                acc = MFMA(c, *(const short8*)(Wl[7] + woff + k), acc);
                acc = MFMA(d, *(const short8*)(Wl[6] + woff + k), acc);
            }
#pragma unroll
            for (int r = 0; r < 4; ++r) gacc[w][g4 * 4 + r][cc] = acc[r];
        }
        __syncthreads();
        if (tid < 128) {
            float gv[4];
#pragma unroll
            for (int q = 0; q < 4; ++q) {
                int lr = q * 8 + jl;
                gv[q] = gacc[lr >> 4][bb][lr & 15] + gacc[2 + (lr >> 4)][bb][lr & 15] + bs1[q];
            }
            float c = sigm(gv[1]) * c1r + sigm(gv[0]) * tanh_f(gv[2]);
            c1r = c;
            float h = sigm(gv[3]) * tanh_f(c);
            short sh, sl; split2s(h, &sh, &sl);
            h1bh[(t & 1) * 4096 + bb * 256 + j] = sh;
            h1bl[(t & 1) * 4096 + bb * 256 + j] = sl;
            preds[((long)(t + 1) * BB + bb) * HH + j] = h;
        }
        gbar(flags, ++gen);
    }
}

// ---------------- host launch ----------------
extern "C" void kernel_launch(void* const* d_in, const int* in_sizes, int n_in,
                              void* d_out, int out_size, void* d_ws, size_t ws_size,
                              hipStream_t stream) {
    const int*   src   = (const int*)  d_in[0];
    const float* te    = (const float*)d_in[2];
    const float* h0    = (const float*)d_in[3];
    const float* c0    = (const float*)d_in[4];
    const float* table = (const float*)d_in[5];
    const float* eWih  = (const float*)d_in[6];
    const float* eWhh  = (const float*)d_in[7];
    const float* ebih  = (const float*)d_in[8];
    const float* ebhh  = (const float*)d_in[9];
    const float* dWih  = (const float*)d_in[10];
    const float* dWhh  = (const float*)d_in[11];
    const float* dbih  = (const float*)d_in[12];
    const float* dbhh  = (const float*)d_in[13];
    float* preds = (float*)d_out;

    const int WN = GG * EE;                  // 262144 elems per layer-matrix
    const size_t MB = 1u << 20;
    char* ws = (char*)d_ws;
    short* eWih_hi = (short*)(ws + 0 * MB);
    short* eWih_lo = (short*)(ws + 1 * MB);
    short* eWhh_hi = (short*)(ws + 2 * MB);
    short* eWhh_lo = (short*)(ws + 3 * MB);
    short* dWih_hi = (short*)(ws + 4 * MB);
    short* dWih_lo = (short*)(ws + 5 * MB);
    short* dWhh_hi = (short*)(ws + 6 * MB);
    short* dWhh_lo = (short*)(ws + 7 * MB);
    short* Xa_hi   = (short*)(ws + 8 * MB);      // [4096,256]
    short* Xa_lo   = (short*)(ws + 10 * MB);
    float* hfin    = (float*)(ws + 12 * MB);     // [2,16,256]
    int*   flags   = (int*)  (ws + 12 * MB + (64 << 10));   // enc: +0, dec: +32
    short* eb      = (short*)(ws + 12 * MB + (128 << 10));  // enc h bufs 4x8192
    short* db      = (short*)(ws + 12 * MB + (256 << 10));  // dec bufs
    float* gates0  = (float*)(ws + 16 * MB);     // [4096,1024] f32

    k_binit<<<1, 64, 0, stream>>>(flags);

    k_cvt2<<<2048, 256, 0, stream>>>(eWih, (__hip_bfloat16*)eWih_hi, (__hip_bfloat16*)eWih_lo, 2 * WN);
    k_cvt2<<<2048, 256, 0, stream>>>(eWhh, (__hip_bfloat16*)eWhh_hi, (__hip_bfloat16*)eWhh_lo, 2 * WN);
    k_cvt2<<<2048, 256, 0, stream>>>(dWih, (__hip_bfloat16*)dWih_hi, (__hip_bfloat16*)dWih_lo, 2 * WN);
    k_cvt2<<<2048, 256, 0, stream>>>(dWhh, (__hip_bfloat16*)dWhh_hi, (__hip_bfloat16*)dWhh_lo, 2 * WN);

    // encoder L0 input-side GEMM (parallel), then cooperative 2-layer wavefront scan
    k_embed<<<4096, 256, 0, stream>>>(src, table, (__hip_bfloat16*)Xa_hi, (__hip_bfloat16*)Xa_lo);
    k_gemm_in<<<4096, 256, 0, stream>>>((__hip_bfloat16*)Xa_hi, (__hip_bfloat16*)Xa_lo,
                                        (__hip_bfloat16*)eWih_hi, (__hip_bfloat16*)eWih_lo,
                                        ebih, ebhh, gates0);
    k_enc_coop<<<NWG, 256, 0, stream>>>(gates0, eWhh_hi, eWhh_lo,
                                        eWih_hi + WN, eWih_lo + WN, eWhh_hi + WN, eWhh_lo + WN,
                                        ebih + GG, ebhh + GG, h0, c0,
                                        eb, eb + 8192, eb + 16384, eb + 24576,
                                        hfin, flags);

    // decoder cooperative scan
    k_dec_coop<<<NWG, 256, 0, stream>>>(dWih_hi, dWih_lo, dWhh_hi, dWhh_lo,
                                        dbih, dbhh, te, hfin,
                                        db, db + 8192, db + 16384, db + 24576,
                                        db + 32768, db + 36864, db + 40960, db + 45056,
                                        db + 49152, db + 53248,
                                        preds, flags + 32);

    // predictions[0] = 0
    k_zero<<<16, 256, 0, stream>>>(preds);
}